// Round 10
// baseline (570.487 us; speedup 1.0000x reference)
//
#include <hip/hip_runtime.h>
#include <hip/hip_bf16.h>
#include <stddef.h>

// Problem constants
#define NB   65536   // batch
#define XC   130     // x row stride (IN+1+LAT)
#define LATD 128
#define HIDD 2048
#define JC   1024    // collapsed output cols (IN+1)*OUT
#define OC   512     // OUT
#define BAND 16384   // rows per band (h staging, 64MB -> L3-resident)
#define WBM  256     // wag tile rows
#define WBN  256     // wag tile collapsed cols
#define BK   64      // wag K-tile
#define NKT  32      // HIDD/BK

typedef __bf16 bf16_t;
typedef bf16_t bf16x4 __attribute__((ext_vector_type(4)));
typedef bf16_t bf16x8 __attribute__((ext_vector_type(8)));
typedef float  f32x4  __attribute__((ext_vector_type(4)));

typedef __attribute__((address_space(1))) const unsigned char ga_u8;
typedef __attribute__((address_space(3))) unsigned char ls_u8;

__device__ __forceinline__ void dma16(const void* g, void* l) {
  __builtin_amdgcn_global_load_lds((ga_u8*)g, (ls_u8*)l, 16, 0, 0);
}

// ---------- prep 1: fc1wT[n][k] = bf16(fc1_w[k][n])
__global__ void prep_fc1(const float* __restrict__ fc1w, bf16_t* __restrict__ fc1wT) {
  int t = blockIdx.x * blockDim.x + threadIdx.x;
  int k = t & (LATD - 1);
  int n = t >> 7;
  fc1wT[(size_t)n * LATD + k] = (bf16_t)fc1w[(size_t)k * HIDD + n];
}

// ---------- prep 2: collapse fc2 against v, permute cols, transpose.
// collapsed c -> g=c>>5, half=(c>>4)&1, col16=c&15; out-col o=g*16+col16; jj=o+half*512.
__global__ void prep_fc2(const float* __restrict__ x, const float* __restrict__ fc2w,
                         const float* __restrict__ fc2b, const float* __restrict__ dil,
                         const float* __restrict__ shp, bf16_t* __restrict__ w2pT,
                         float* __restrict__ b2p) {
  int t = blockIdx.x * blockDim.x + threadIdx.x;
  int k = t & (HIDD - 1);
  int c = t >> 11;
  float s  = x[(size_t)(NB - 1) * XC + 1];
  float t0 = s * dil[0] + shp[0];
  float t1 = s * dil[1] + shp[1];
  float t2 = s * dil[2] + shp[2];
  float t3 = s * dil[3] + shp[3];
  float v0 = cosf(t0) + cosf(t2);
  float v1 = sinf(t1) + sinf(t3);
  int jj = ((c >> 5) * 16 + (c & 15)) + (((c >> 4) & 1) << 9);
  float w0 = fc2w[(size_t)k * 2048 + 2 * jj];
  float w1 = fc2w[(size_t)k * 2048 + 2 * jj + 1];
  w2pT[(size_t)c * HIDD + k] = (bf16_t)(w0 * v0 + w1 * v1);
  if (k == 0) b2p[c] = fc2b[2 * jj] * v0 + fc2b[2 * jj + 1] * v1;
}

// ---------- h kernel v2: streaming, barrier-free, zero-LDS.
// 256 blocks x 512 thr; block = 64 rows. Wave w: hid-16 half hb=w&1 within each
// 32-chunk, batch-16 group gb=(w>>1)*16. Swapped MFMA (round-7 verified):
// D[hid-k][batch] = fc1_frag x z_frag -> lane holds 4 consecutive hid-k for one
// batch row -> packed b64 row-major store. 4-deep fc1 fragment pipeline.
__global__ __launch_bounds__(512) void h_kernel(
    const float* __restrict__ x, const float* __restrict__ fc1b,
    const bf16_t* __restrict__ fc1wT, bf16_t* __restrict__ h, int band)
{
  const int t   = threadIdx.x;
  const int w   = t >> 6;
  const int l   = t & 63;
  const int lhi = l >> 4;
  const int llo = l & 15;
  const size_t b0 = (size_t)band * BAND + (size_t)blockIdx.x * 64;
  const int hb  = w & 1;
  const int gb  = (w >> 1) * 16;
  const size_t row_l = (size_t)blockIdx.x * 64 + gb + llo;   // band-local store row

  // z fragment for this lane's batch row (K=128)
  bf16x8 za[4];
  {
    const float* zsrc = x + (b0 + gb + llo) * XC + 2;
#pragma unroll
    for (int ks = 0; ks < 4; ++ks) {
      bf16x8 pk;
#pragma unroll
      for (int i = 0; i < 4; ++i) {
        float2 f = *(const float2*)(zsrc + ks * 32 + lhi * 8 + 2 * i);
        pk[2 * i]     = (bf16_t)f.x;
        pk[2 * i + 1] = (bf16_t)f.y;
      }
      za[ks] = pk;
    }
  }

  auto loadA = [&](bf16x8 (&A)[4], int c) {   // fc1 fragment, 4x16B from L2
    const bf16_t* base = fc1wT + (size_t)(c * 32 + hb * 16 + llo) * LATD + lhi * 8;
#pragma unroll
    for (int ks = 0; ks < 4; ++ks) A[ks] = *(const bf16x8*)(base + ks * 32);
  };
  auto compute = [&](int c, bf16x8 (&A)[4]) {
    f32x4 c1 = {};
#pragma unroll
    for (int ks = 0; ks < 4; ++ks)
      c1 = __builtin_amdgcn_mfma_f32_16x16x32_bf16(A[ks], za[ks], c1, 0, 0, 0);
    float4 fb = *(const float4*)(fc1b + c * 32 + hb * 16 + lhi * 4);
    bf16x4 pk;
#pragma unroll
    for (int r = 0; r < 4; ++r) {
      float pre = c1[r] + ((const float*)&fb)[r];
      float e   = __builtin_amdgcn_exp2f(pre * 2.88539008177792681f);  // e^(2x)
      float th  = 1.0f - 2.0f * __builtin_amdgcn_rcpf(e + 1.0f);
      pk[r] = (bf16_t)th;
    }
    *(bf16x4*)(h + row_l * HIDD + c * 32 + hb * 16 + lhi * 4) = pk;
  };

  bf16x8 A0[4], A1[4], A2[4], A3[4];
  loadA(A0, 0); loadA(A1, 1); loadA(A2, 2); loadA(A3, 3);
  for (int c = 0; c < 64; c += 4) {
    compute(c,     A0);  loadA(A0, c + 4 < 64 ? c + 4 : 63);
    compute(c + 1, A1);  loadA(A1, c + 5 < 64 ? c + 5 : 63);
    compute(c + 2, A2);  loadA(A2, c + 6 < 64 ? c + 6 : 63);
    compute(c + 3, A3);  loadA(A3, c + 7 < 64 ? c + 7 : 63);
  }
}

// ---------- wag_main: 256x256-tile GEMM acc += h_band @ w2pT^T, K=2048.
// Round-9 verified schedule (counted vmcnt, 2 raw barriers/K-tile) unchanged.
// NEW: 1-D grid + bijective XCD swizzle so the 4 col-group blocks of each
// row-tile run on the SAME XCD -> A-tile fetched from L3 once, L2-hit 3x.
__global__ __launch_bounds__(512, 2) void wag_main(
    const float* __restrict__ x, const bf16_t* __restrict__ hband,
    const bf16_t* __restrict__ w2pT, const float* __restrict__ b2p,
    float* __restrict__ out, int band)
{
  __shared__ bf16_t Ab[2][WBM * BK];    // 2x32KB
  __shared__ bf16_t Bb[2][WBN * BK];    // 2x32KB
  __shared__ float  inp_lds[WBM];

  const int t   = threadIdx.x;
  const int w   = t >> 6;
  const int l   = t & 63;
  const int lhi = l >> 4;
  const int llo = l & 15;

  // XCD swizzle: n%8 = XCD (hw round-robin). XCD x owns row-tiles x*8..x*8+7,
  // all 4 col-groups co-resident on that XCD (32 blocks/XCD, 1 block/CU).
  const int n   = blockIdx.x;
  const int s_  = n >> 3;
  const int rt  = (n & 7) * 8 + (s_ >> 2);
  const int cg  = s_ & 3;
  const int hr0 = rt * WBM;                         // band-local row base
  const size_t bg0 = (size_t)band * BAND + hr0;     // global row base
  const int bc  = cg * WBN;
  const int mrb = (w >> 2) * 128;
  const int ncb = (w & 3) * 64;

  if (t < WBM) inp_lds[t] = x[(bg0 + t) * XC];

  f32x4 acc[8][4] = {};

  auto stageA = [&](int kt) {
    bf16_t* dst = Ab[kt & 1];
#pragma unroll
    for (int q = 0; q < 4; ++q) {
      int idx  = q * 512 + t;
      int row  = idx >> 3, slot = idx & 7;
      const char* src = (const char*)(hband + (size_t)(hr0 + row) * HIDD + kt * BK
                                      + ((slot ^ (row & 7)) * 8));
      dma16(src, (char*)dst + idx * 16);
    }
  };
  auto stageB = [&](int kt) {
    bf16_t* dst = Bb[kt & 1];
#pragma unroll
    for (int q = 0; q < 4; ++q) {
      int idx  = q * 512 + t;
      int col  = idx >> 3, slot = idx & 7;
      const char* src = (const char*)(w2pT + (size_t)(bc + col) * HIDD + kt * BK
                                      + ((slot ^ (col & 7)) * 8));
      dma16(src, (char*)dst + idx * 16);
    }
  };

  auto KSTEP = [&](int kt) {
    const char* Ab_ = (const char*)Ab[kt & 1];
    const char* Bb_ = (const char*)Bb[kt & 1];
#pragma unroll
    for (int ks2 = 0; ks2 < 2; ++ks2) {
      bf16x8 b[4];
#pragma unroll
      for (int j = 0; j < 4; ++j) {
        int col = ncb + j * 16 + llo;
        b[j] = *(const bf16x8*)(Bb_ + col * 128 + ((ks2 * 64 + lhi * 16) ^ ((col & 7) << 4)));
      }
#pragma unroll
      for (int rh = 0; rh < 2; ++rh) {
        bf16x8 a[4];
#pragma unroll
        for (int i = 0; i < 4; ++i) {
          int row = mrb + rh * 64 + i * 16 + llo;
          a[i] = *(const bf16x8*)(Ab_ + row * 128 + ((ks2 * 64 + lhi * 16) ^ ((row & 7) << 4)));
        }
        __builtin_amdgcn_s_setprio(1);
#pragma unroll
        for (int j = 0; j < 4; ++j)
#pragma unroll
          for (int i = 0; i < 4; ++i)
            acc[rh * 4 + i][j] =
                __builtin_amdgcn_mfma_f32_16x16x32_bf16(a[i], b[j], acc[rh * 4 + i][j], 0, 0, 0);
        __builtin_amdgcn_s_setprio(0);
      }
    }
  };

  stageA(0); stageB(0);
  __syncthreads();                       // prologue full drain: tile 0 ready
  for (int kt = 0; kt < NKT - 1; ++kt) {
    stageA(kt + 1); stageB(kt + 1);      // 8 VM ops -> buf^1, in flight across bars
    asm volatile("s_waitcnt vmcnt(8)" ::: "memory");   // tile kt complete (counted)
    __builtin_amdgcn_s_barrier();        // bar#1: RAW — tile kt visible to all
    KSTEP(kt);
    asm volatile("s_waitcnt lgkmcnt(0)" ::: "memory");
    __builtin_amdgcn_s_barrier();        // bar#2: WAR — reads done before next stage
  }
  asm volatile("s_waitcnt vmcnt(0)" ::: "memory");     // tail drain (once)
  __builtin_amdgcn_s_barrier();
  KSTEP(NKT - 1);

  // ---- epilogue: weight (frag 2p) / bias (frag 2p+1) in SAME lane; 64B stores
#pragma unroll
  for (int p = 0; p < 2; ++p) {
    int cw = bc + ncb + p * 32 + llo;
    float bw = b2p[cw];
    float bb = b2p[cw + 16];
    int oc = (bc + ncb + p * 32) / 2 + llo;
#pragma unroll
    for (int fi = 0; fi < 8; ++fi) {
#pragma unroll
      for (int r = 0; r < 4; ++r) {
        int row = mrb + fi * 16 + lhi * 4 + r;
        float wv = acc[fi][2 * p][r] + bw;
        float bv = acc[fi][2 * p + 1][r] + bb;
        out[(bg0 + row) * OC + oc] = inp_lds[row] * wv + bv;
      }
    }
  }
}

extern "C" void kernel_launch(void* const* d_in, const int* in_sizes, int n_in,
                              void* d_out, int out_size, void* d_ws, size_t ws_size,
                              hipStream_t stream) {
  const float* x    = (const float*)d_in[0];
  const float* fc1w = (const float*)d_in[1];
  const float* fc1b = (const float*)d_in[2];
  const float* fc2w = (const float*)d_in[3];
  const float* fc2b = (const float*)d_in[4];
  const float* dil  = (const float*)d_in[5];
  const float* shp  = (const float*)d_in[6];
  float* out = (float*)d_out;

  // ws: fc1wT 512KB | w2pT 4MB | b2p 4KB | ... | hband 64MB at +8MB  (72MB total)
  bf16_t* fc1wT = (bf16_t*)d_ws;
  bf16_t* w2pT  = fc1wT + (size_t)HIDD * LATD;
  float*  b2p   = (float*)(w2pT + (size_t)JC * HIDD);
  bf16_t* hband = (bf16_t*)((char*)d_ws + (8u << 20));

  prep_fc1<<<(HIDD * LATD) / 256, 256, 0, stream>>>(fc1w, fc1wT);
  prep_fc2<<<(JC * HIDD) / 256, 256, 0, stream>>>(x, fc2w, fc2b, dil, shp, w2pT, b2p);

  for (int band = 0; band < NB / BAND; ++band) {
    h_kernel<<<BAND / 64, 512, 0, stream>>>(x, fc1b, fc1wT, hband, band);
    wag_main<<<WBM == 256 ? (BAND / WBM) * (JC / WBN) : 0, 512, 0, stream>>>(
        x, hband, w2pT, b2p, out, band);
  }
}

// Round 11
// 550.887 us; speedup vs baseline: 1.0356x; 1.0356x over previous
//
#include <hip/hip_runtime.h>
#include <hip/hip_bf16.h>
#include <stddef.h>

// Problem constants
#define NB   65536   // batch
#define XC   130     // x row stride (IN+1+LAT)
#define LATD 128
#define HIDD 2048
#define JC   1024    // collapsed output cols (IN+1)*OUT
#define OC   512     // OUT
#define BAND 16384   // rows per band (h staging, 64MB -> L3-resident)
#define WBM  256     // wag tile rows
#define WBN  256     // wag tile collapsed cols
#define BK   64      // wag K-tile
#define NKT  32      // HIDD/BK

typedef __bf16 bf16_t;
typedef bf16_t bf16x4 __attribute__((ext_vector_type(4)));
typedef bf16_t bf16x8 __attribute__((ext_vector_type(8)));
typedef float  f32x4  __attribute__((ext_vector_type(4)));

typedef __attribute__((address_space(1))) const unsigned char ga_u8;
typedef __attribute__((address_space(3))) unsigned char ls_u8;

__device__ __forceinline__ void dma16(const void* g, void* l) {
  __builtin_amdgcn_global_load_lds((ga_u8*)g, (ls_u8*)l, 16, 0, 0);
}

// ---------- prep 1: fc1wT[n][k] = bf16(fc1_w[k][n])
__global__ void prep_fc1(const float* __restrict__ fc1w, bf16_t* __restrict__ fc1wT) {
  int t = blockIdx.x * blockDim.x + threadIdx.x;
  int k = t & (LATD - 1);
  int n = t >> 7;
  fc1wT[(size_t)n * LATD + k] = (bf16_t)fc1w[(size_t)k * HIDD + n];
}

// ---------- prep 2 (LDS-transposed): collapse fc2 against v, permute, transpose.
// collapsed c: g=c>>5, half=(c>>4)&1, col16=c&15; jj = g*16+col16+half*512.
// w2pT[c][k] = bf16(fc2w[k][2jj]*v0 + fc2w[k][2jj+1]*v1).
// Block: g = blockIdx.x (32 cols), k-tile = blockIdx.y*128. Coalesced both sides.
__global__ __launch_bounds__(256) void prep_fc2(
    const float* __restrict__ x, const float* __restrict__ fc2w,
    const float* __restrict__ fc2b, const float* __restrict__ dil,
    const float* __restrict__ shp, bf16_t* __restrict__ w2pT,
    float* __restrict__ b2p) {
  __shared__ float tile[128 * 67];   // rows padded to 67 words
  const int t  = threadIdx.x;
  const int g  = blockIdx.x;
  const int k0 = blockIdx.y * 128;

  float s  = x[(size_t)(NB - 1) * XC + 1];
  float t0 = s * dil[0] + shp[0];
  float t1 = s * dil[1] + shp[1];
  float t2 = s * dil[2] + shp[2];
  float t3 = s * dil[3] + shp[3];
  float v0 = cosf(t0) + cosf(t2);
  float v1 = sinf(t1) + sinf(t3);

  // load: 128 k-rows x 64 floats (two 128B runs per row: half0 @ g*32, half1 @ 1024+g*32)
  {
    int fi_ = t & 63, run = fi_ >> 5, fi = fi_ & 31, wv = t >> 6;
#pragma unroll 8
    for (int pass = 0; pass < 32; ++pass) {
      int kr = pass * 4 + wv;
      tile[kr * 67 + run * 32 + fi] =
          fc2w[(size_t)(k0 + kr) * 2048 + run * 1024 + g * 32 + fi];
    }
  }
  __syncthreads();

  // compute: thread -> c_local = t>>3, k-seg = (t&7)*16 (16 consecutive k)
  {
    int cl = t >> 3, half = (cl >> 4) & 1, col16 = cl & 15;
    int c = g * 32 + cl;
    int pb = half * 32 + col16 * 2;
    bf16x8 ov0, ov1;
#pragma unroll
    for (int kk = 0; kk < 16; ++kk) {
      int k = (t & 7) * 16 + kk;
      float f0 = tile[k * 67 + pb];
      float f1 = tile[k * 67 + pb + 1];
      bf16_t bv = (bf16_t)(f0 * v0 + f1 * v1);
      if (kk < 8) ov0[kk] = bv; else ov1[kk - 8] = bv;
    }
    *(bf16x8*)(w2pT + (size_t)c * 2048 + k0 + (t & 7) * 16)     = ov0;
    *(bf16x8*)(w2pT + (size_t)c * 2048 + k0 + (t & 7) * 16 + 8) = ov1;
    if (blockIdx.y == 0 && (t & 7) == 0) {
      int jj = g * 16 + col16 + (half << 9);
      b2p[c] = fc2b[2 * jj] * v0 + fc2b[2 * jj + 1] * v1;
    }
  }
}

// ---------- h kernel v3: swapped-MFMA + LDS regroup -> 512B-contiguous stores.
// 512 blocks x 512 thr; block = 32 rows. Wave w: rows (w&1)*16, hid quarter (w>>1)*512.
// Per 16-col group: 4 MFMA (D[hid][batch], lane = 4 consec hid-k of one batch row)
// -> tanh -> ONE ds_write_b64 into per-wave tile (pitch 528B). After 16 groups
// (256 cols), readback: 8 instrs, each storing 2 rows x 512B contiguous.
__global__ __launch_bounds__(512, 4) void h_kernel(
    const float* __restrict__ x, const float* __restrict__ fc1b,
    const bf16_t* __restrict__ fc1wT, bf16_t* __restrict__ h, int band)
{
  __shared__ char tile[8][16 * 528];    // 67.6KB
  const int t   = threadIdx.x;
  const int w   = t >> 6;
  const int l   = t & 63;
  const int lhi = l >> 4;
  const int llo = l & 15;
  const size_t b0 = (size_t)band * BAND + (size_t)blockIdx.x * 32;
  const int rg  = (w & 1) * 16;         // row-group base (block-local)
  const int H0  = (w >> 1) * 512;       // hid quarter
  char* tw = tile[w];

  // z fragment for batch row b0+rg+llo (K=128)
  bf16x8 za[4];
  {
    const float* zsrc = x + (b0 + rg + llo) * XC + 2;
#pragma unroll
    for (int ks = 0; ks < 4; ++ks) {
      bf16x8 pk;
#pragma unroll
      for (int i = 0; i < 4; ++i) {
        float2 f = *(const float2*)(zsrc + ks * 32 + lhi * 8 + 2 * i);
        pk[2 * i]     = (bf16_t)f.x;
        pk[2 * i + 1] = (bf16_t)f.y;
      }
      za[ks] = pk;
    }
  }

  auto loadA = [&](bf16x8 (&A)[4], int cpos) {   // fc1 fragment for 16-col group cpos
    const bf16_t* base = fc1wT + (size_t)(H0 + cpos * 16 + llo) * LATD + lhi * 8;
#pragma unroll
    for (int ks = 0; ks < 4; ++ks) A[ks] = *(const bf16x8*)(base + ks * 32);
  };
  auto compute = [&](int cpos, bf16x8 (&A)[4]) {
    f32x4 c1 = {};
#pragma unroll
    for (int ks = 0; ks < 4; ++ks)
      c1 = __builtin_amdgcn_mfma_f32_16x16x32_bf16(A[ks], za[ks], c1, 0, 0, 0);
    float4 fb = *(const float4*)(fc1b + H0 + cpos * 16 + lhi * 4);
    bf16x4 pk;
#pragma unroll
    for (int r = 0; r < 4; ++r) {
      float pre = c1[r] + ((const float*)&fb)[r];
      float e   = __builtin_amdgcn_exp2f(pre * 2.88539008177792681f);   // e^(2x)
      float th  = 1.0f - 2.0f * __builtin_amdgcn_rcpf(e + 1.0f);
      pk[r] = (bf16_t)th;
    }
    // lane holds hid-k lhi*4..+4 of batch row llo
    *(bf16x4*)(tw + llo * 528 + (cpos & 15) * 32 + lhi * 8) = pk;
  };

  for (int half = 0; half < 2; ++half) {
    bf16x8 A0[4], A1[4];
    loadA(A0, half * 16 + 0);
    loadA(A1, half * 16 + 1);
#pragma unroll
    for (int nt = 0; nt < 16; nt += 2) {
      compute(half * 16 + nt, A0);
      if (nt + 2 < 16) loadA(A0, half * 16 + nt + 2);
      compute(half * 16 + nt + 1, A1);
      if (nt + 3 < 16) loadA(A1, half * 16 + nt + 3);
    }
    // readback: 2 rows x 512B contiguous per instruction
#pragma unroll
    for (int rr = 0; rr < 8; ++rr) {
      int row = rr * 2 + (l >> 5);
      int seg = l & 31;
      bf16x8 v = *(const bf16x8*)(tw + row * 528 + seg * 16);
      *(bf16x8*)(h + (size_t)(blockIdx.x * 32 + rg + row) * HIDD
                   + H0 + half * 256 + seg * 8) = v;
    }
  }
}

// ---------- wag_main: 256x256-tile GEMM acc += h_band @ w2pT^T, K=2048.
// Counted-vmcnt schedule + XCD co-location swizzle (round-10 verified, unchanged).
__global__ __launch_bounds__(512, 2) void wag_main(
    const float* __restrict__ x, const bf16_t* __restrict__ hband,
    const bf16_t* __restrict__ w2pT, const float* __restrict__ b2p,
    float* __restrict__ out, int band)
{
  __shared__ bf16_t Ab[2][WBM * BK];    // 2x32KB
  __shared__ bf16_t Bb[2][WBN * BK];    // 2x32KB
  __shared__ float  inp_lds[WBM];

  const int t   = threadIdx.x;
  const int w   = t >> 6;
  const int l   = t & 63;
  const int lhi = l >> 4;
  const int llo = l & 15;

  const int n   = blockIdx.x;
  const int s_  = n >> 3;
  const int rt  = (n & 7) * 8 + (s_ >> 2);
  const int cg  = s_ & 3;
  const int hr0 = rt * WBM;
  const size_t bg0 = (size_t)band * BAND + hr0;
  const int bc  = cg * WBN;
  const int mrb = (w >> 2) * 128;
  const int ncb = (w & 3) * 64;

  if (t < WBM) inp_lds[t] = x[(bg0 + t) * XC];

  f32x4 acc[8][4] = {};

  auto stageA = [&](int kt) {
    bf16_t* dst = Ab[kt & 1];
#pragma unroll
    for (int q = 0; q < 4; ++q) {
      int idx  = q * 512 + t;
      int row  = idx >> 3, slot = idx & 7;
      const char* src = (const char*)(hband + (size_t)(hr0 + row) * HIDD + kt * BK
                                      + ((slot ^ (row & 7)) * 8));
      dma16(src, (char*)dst + idx * 16);
    }
  };
  auto stageB = [&](int kt) {
    bf16_t* dst = Bb[kt & 1];
#pragma unroll
    for (int q = 0; q < 4; ++q) {
      int idx  = q * 512 + t;
      int col  = idx >> 3, slot = idx & 7;
      const char* src = (const char*)(w2pT + (size_t)(bc + col) * HIDD + kt * BK
                                      + ((slot ^ (col & 7)) * 8));
      dma16(src, (char*)dst + idx * 16);
    }
  };

  auto KSTEP = [&](int kt) {
    const char* Ab_ = (const char*)Ab[kt & 1];
    const char* Bb_ = (const char*)Bb[kt & 1];
#pragma unroll
    for (int ks2 = 0; ks2 < 2; ++ks2) {
      bf16x8 b[4];
#pragma unroll
      for (int j = 0; j < 4; ++j) {
        int col = ncb + j * 16 + llo;
        b[j] = *(const bf16x8*)(Bb_ + col * 128 + ((ks2 * 64 + lhi * 16) ^ ((col & 7) << 4)));
      }
#pragma unroll
      for (int rh = 0; rh < 2; ++rh) {
        bf16x8 a[4];
#pragma unroll
        for (int i = 0; i < 4; ++i) {
          int row = mrb + rh * 64 + i * 16 + llo;
          a[i] = *(const bf16x8*)(Ab_ + row * 128 + ((ks2 * 64 + lhi * 16) ^ ((row & 7) << 4)));
        }
        __builtin_amdgcn_s_setprio(1);
#pragma unroll
        for (int j = 0; j < 4; ++j)
#pragma unroll
          for (int i = 0; i < 4; ++i)
            acc[rh * 4 + i][j] =
                __builtin_amdgcn_mfma_f32_16x16x32_bf16(a[i], b[j], acc[rh * 4 + i][j], 0, 0, 0);
        __builtin_amdgcn_s_setprio(0);
      }
    }
  };

  stageA(0); stageB(0);
  __syncthreads();
  for (int kt = 0; kt < NKT - 1; ++kt) {
    stageA(kt + 1); stageB(kt + 1);
    asm volatile("s_waitcnt vmcnt(8)" ::: "memory");
    __builtin_amdgcn_s_barrier();
    KSTEP(kt);
    asm volatile("s_waitcnt lgkmcnt(0)" ::: "memory");
    __builtin_amdgcn_s_barrier();
  }
  asm volatile("s_waitcnt vmcnt(0)" ::: "memory");
  __builtin_amdgcn_s_barrier();
  KSTEP(NKT - 1);

#pragma unroll
  for (int p = 0; p < 2; ++p) {
    int cw = bc + ncb + p * 32 + llo;
    float bw = b2p[cw];
    float bb = b2p[cw + 16];
    int oc = (bc + ncb + p * 32) / 2 + llo;
#pragma unroll
    for (int fi = 0; fi < 8; ++fi) {
#pragma unroll
      for (int r = 0; r < 4; ++r) {
        int row = mrb + fi * 16 + lhi * 4 + r;
        float wv = acc[fi][2 * p][r] + bw;
        float bv = acc[fi][2 * p + 1][r] + bb;
        out[(bg0 + row) * OC + oc] = inp_lds[row] * wv + bv;
      }
    }
  }
}

extern "C" void kernel_launch(void* const* d_in, const int* in_sizes, int n_in,
                              void* d_out, int out_size, void* d_ws, size_t ws_size,
                              hipStream_t stream) {
  const float* x    = (const float*)d_in[0];
  const float* fc1w = (const float*)d_in[1];
  const float* fc1b = (const float*)d_in[2];
  const float* fc2w = (const float*)d_in[3];
  const float* fc2b = (const float*)d_in[4];
  const float* dil  = (const float*)d_in[5];
  const float* shp  = (const float*)d_in[6];
  float* out = (float*)d_out;

  // ws: fc1wT 512KB | w2pT 4MB | b2p 4KB | ... | hband 64MB at +8MB
  bf16_t* fc1wT = (bf16_t*)d_ws;
  bf16_t* w2pT  = fc1wT + (size_t)HIDD * LATD;
  float*  b2p   = (float*)(w2pT + (size_t)JC * HIDD);
  bf16_t* hband = (bf16_t*)((char*)d_ws + (8u << 20));

  prep_fc1<<<(HIDD * LATD) / 256, 256, 0, stream>>>(fc1w, fc1wT);
  prep_fc2<<<dim3(32, 16), 256, 0, stream>>>(x, fc2w, fc2b, dil, shp, w2pT, b2p);

  for (int band = 0; band < NB / BAND; ++band) {
    h_kernel<<<BAND / 32, 512, 0, stream>>>(x, fc1b, fc1wT, hband, band);
    wag_main<<<(BAND / WBM) * (JC / WBN), 512, 0, stream>>>(
        x, hband, w2pT, b2p, out, band);
  }
}

// Round 12
// 547.357 us; speedup vs baseline: 1.0423x; 1.0064x over previous
//
#include <hip/hip_runtime.h>
#include <hip/hip_bf16.h>
#include <stddef.h>

// Problem constants
#define NB   65536   // batch
#define XC   130     // x row stride (IN+1+LAT)
#define LATD 128
#define HIDD 2048
#define JC   1024    // collapsed output cols (IN+1)*OUT
#define OC   512     // OUT
#define BAND 16384   // rows per band (h staging, 64MB -> L3-resident)
#define WBM  256     // wag tile rows
#define WBN  256     // wag tile collapsed cols
#define BK   64      // wag K-tile
#define NKT  32      // HIDD/BK

typedef __bf16 bf16_t;
typedef bf16_t bf16x4 __attribute__((ext_vector_type(4)));
typedef bf16_t bf16x8 __attribute__((ext_vector_type(8)));
typedef float  f32x4  __attribute__((ext_vector_type(4)));

typedef __attribute__((address_space(1))) const unsigned char ga_u8;
typedef __attribute__((address_space(3))) unsigned char ls_u8;

__device__ __forceinline__ void dma16(const void* g, void* l) {
  __builtin_amdgcn_global_load_lds((ga_u8*)g, (ls_u8*)l, 16, 0, 0);
}

// ---------- prep 1: fc1wT[n][k] = bf16(fc1_w[k][n])
__global__ void prep_fc1(const float* __restrict__ fc1w, bf16_t* __restrict__ fc1wT) {
  int t = blockIdx.x * blockDim.x + threadIdx.x;
  int k = t & (LATD - 1);
  int n = t >> 7;
  fc1wT[(size_t)n * LATD + k] = (bf16_t)fc1w[(size_t)k * HIDD + n];
}

// ---------- prep 2 (LDS-transposed): collapse fc2 against v, permute, transpose.
__global__ __launch_bounds__(256) void prep_fc2(
    const float* __restrict__ x, const float* __restrict__ fc2w,
    const float* __restrict__ fc2b, const float* __restrict__ dil,
    const float* __restrict__ shp, bf16_t* __restrict__ w2pT,
    float* __restrict__ b2p) {
  __shared__ float tile[128 * 67];   // rows padded to 67 words
  const int t  = threadIdx.x;
  const int g  = blockIdx.x;
  const int k0 = blockIdx.y * 128;

  float s  = x[(size_t)(NB - 1) * XC + 1];
  float t0 = s * dil[0] + shp[0];
  float t1 = s * dil[1] + shp[1];
  float t2 = s * dil[2] + shp[2];
  float t3 = s * dil[3] + shp[3];
  float v0 = cosf(t0) + cosf(t2);
  float v1 = sinf(t1) + sinf(t3);

  {
    int fi_ = t & 63, run = fi_ >> 5, fi = fi_ & 31, wv = t >> 6;
#pragma unroll 8
    for (int pass = 0; pass < 32; ++pass) {
      int kr = pass * 4 + wv;
      tile[kr * 67 + run * 32 + fi] =
          fc2w[(size_t)(k0 + kr) * 2048 + run * 1024 + g * 32 + fi];
    }
  }
  __syncthreads();

  {
    int cl = t >> 3, half = (cl >> 4) & 1, col16 = cl & 15;
    int c = g * 32 + cl;
    int pb = half * 32 + col16 * 2;
    bf16x8 ov0, ov1;
#pragma unroll
    for (int kk = 0; kk < 16; ++kk) {
      int k = (t & 7) * 16 + kk;
      float f0 = tile[k * 67 + pb];
      float f1 = tile[k * 67 + pb + 1];
      bf16_t bv = (bf16_t)(f0 * v0 + f1 * v1);
      if (kk < 8) ov0[kk] = bv; else ov1[kk - 8] = bv;
    }
    *(bf16x8*)(w2pT + (size_t)c * 2048 + k0 + (t & 7) * 16)     = ov0;
    *(bf16x8*)(w2pT + (size_t)c * 2048 + k0 + (t & 7) * 16 + 8) = ov1;
    if (blockIdx.y == 0 && (t & 7) == 0) {
      int jj = g * 16 + col16 + (half << 9);
      b2p[c] = fc2b[2 * jj] * v0 + fc2b[2 * jj + 1] * v1;
    }
  }
}

// ---------- h kernel v4: swapped-MFMA + small LDS regroup tile, fc1b in LDS.
// 512 blocks x 512 thr; block = 32 rows; wave w: rows (w&1)*16, hid quarter (w>>1)*512.
// Changes vs v3: (1) fc1b staged to LDS once (kills per-group global load on the
// tanh dep chain); (2) 272B-pitch tile flushed every 8 groups (42.8KB LDS total
// -> 3 blocks/CU, 6 waves/SIMD); (3) b128 readback: 4 rows x 256B per store instr.
__global__ __launch_bounds__(512, 6) void h_kernel(
    const float* __restrict__ x, const float* __restrict__ fc1b,
    const bf16_t* __restrict__ fc1wT, bf16_t* __restrict__ h, int band)
{
  __shared__ char tile[8][16 * 272];    // 34.8KB
  __shared__ float fbl[HIDD];           // 8KB
  const int t   = threadIdx.x;
  const int w   = t >> 6;
  const int l   = t & 63;
  const int lhi = l >> 4;
  const int llo = l & 15;
  const size_t b0 = (size_t)band * BAND + (size_t)blockIdx.x * 32;
  const int rg  = (w & 1) * 16;         // row-group base (block-local)
  const int H0  = (w >> 1) * 512;       // hid quarter
  char* tw = tile[w];

  ((float4*)fbl)[t] = ((const float4*)fc1b)[t];   // 512 x 16B = 8KB

  // z fragment for batch row b0+rg+llo (K=128)
  bf16x8 za[4];
  {
    const float* zsrc = x + (b0 + rg + llo) * XC + 2;
#pragma unroll
    for (int ks = 0; ks < 4; ++ks) {
      bf16x8 pk;
#pragma unroll
      for (int i = 0; i < 4; ++i) {
        float2 f = *(const float2*)(zsrc + ks * 32 + lhi * 8 + 2 * i);
        pk[2 * i]     = (bf16_t)f.x;
        pk[2 * i + 1] = (bf16_t)f.y;
      }
      za[ks] = pk;
    }
  }
  __syncthreads();                      // fbl visible

  auto loadA = [&](bf16x8 (&A)[4], int gg) {   // fc1 fragment for 16-col group gg
    const bf16_t* base = fc1wT + (size_t)(H0 + gg * 16 + llo) * LATD + lhi * 8;
#pragma unroll
    for (int ks = 0; ks < 4; ++ks) A[ks] = *(const bf16x8*)(base + ks * 32);
  };
  auto compute = [&](int gg, bf16x8 (&A)[4]) {
    f32x4 c1 = {};
#pragma unroll
    for (int ks = 0; ks < 4; ++ks)
      c1 = __builtin_amdgcn_mfma_f32_16x16x32_bf16(A[ks], za[ks], c1, 0, 0, 0);
    float4 fb = *(const float4*)(&fbl[H0 + gg * 16 + lhi * 4]);  // LDS broadcast
    bf16x4 pk;
#pragma unroll
    for (int r = 0; r < 4; ++r) {
      float pre = c1[r] + ((const float*)&fb)[r];
      float e   = __builtin_amdgcn_exp2f(pre * 2.88539008177792681f);   // e^(2x)
      float th  = 1.0f - 2.0f * __builtin_amdgcn_rcpf(e + 1.0f);
      pk[r] = (bf16_t)th;
    }
    // lane holds hid-k lhi*4..+4 of batch row llo; flush-local col slot gg&7
    *(bf16x4*)(tw + llo * 272 + (gg & 7) * 32 + lhi * 8) = pk;
  };
  auto flush = [&](int fl) {            // 128 cols -> 4 instrs, 4 rows x 256B each
#pragma unroll
    for (int rr = 0; rr < 4; ++rr) {
      int row = rr * 4 + (l >> 4);
      int seg = l & 15;
      bf16x8 v = *(const bf16x8*)(tw + row * 272 + seg * 16);
      *(bf16x8*)(h + (size_t)(blockIdx.x * 32 + rg + row) * HIDD
                   + H0 + fl * 128 + seg * 8) = v;
    }
  };

  bf16x8 A0[4], A1[4];
  loadA(A0, 0); loadA(A1, 1);
  for (int gg = 0; gg < 32; gg += 2) {
    compute(gg, A0);
    loadA(A0, gg + 2 < 32 ? gg + 2 : 31);
    compute(gg + 1, A1);
    loadA(A1, gg + 3 < 32 ? gg + 3 : 31);
    if ((gg & 7) == 6) flush(gg >> 3);
  }
}

// ---------- wag_main: 256x256-tile GEMM acc += h_band @ w2pT^T, K=2048.
// Counted-vmcnt schedule + XCD co-location swizzle (rounds 9-11 verified).
// UNCHANGED: at its staging-bandwidth structural limit (~2.1GB staged total).
__global__ __launch_bounds__(512, 2) void wag_main(
    const float* __restrict__ x, const bf16_t* __restrict__ hband,
    const bf16_t* __restrict__ w2pT, const float* __restrict__ b2p,
    float* __restrict__ out, int band)
{
  __shared__ bf16_t Ab[2][WBM * BK];    // 2x32KB
  __shared__ bf16_t Bb[2][WBN * BK];    // 2x32KB
  __shared__ float  inp_lds[WBM];

  const int t   = threadIdx.x;
  const int w   = t >> 6;
  const int l   = t & 63;
  const int lhi = l >> 4;
  const int llo = l & 15;

  const int n   = blockIdx.x;
  const int s_  = n >> 3;
  const int rt  = (n & 7) * 8 + (s_ >> 2);
  const int cg  = s_ & 3;
  const int hr0 = rt * WBM;
  const size_t bg0 = (size_t)band * BAND + hr0;
  const int bc  = cg * WBN;
  const int mrb = (w >> 2) * 128;
  const int ncb = (w & 3) * 64;

  if (t < WBM) inp_lds[t] = x[(bg0 + t) * XC];

  f32x4 acc[8][4] = {};

  auto stageA = [&](int kt) {
    bf16_t* dst = Ab[kt & 1];
#pragma unroll
    for (int q = 0; q < 4; ++q) {
      int idx  = q * 512 + t;
      int row  = idx >> 3, slot = idx & 7;
      const char* src = (const char*)(hband + (size_t)(hr0 + row) * HIDD + kt * BK
                                      + ((slot ^ (row & 7)) * 8));
      dma16(src, (char*)dst + idx * 16);
    }
  };
  auto stageB = [&](int kt) {
    bf16_t* dst = Bb[kt & 1];
#pragma unroll
    for (int q = 0; q < 4; ++q) {
      int idx  = q * 512 + t;
      int col  = idx >> 3, slot = idx & 7;
      const char* src = (const char*)(w2pT + (size_t)(bc + col) * HIDD + kt * BK
                                      + ((slot ^ (col & 7)) * 8));
      dma16(src, (char*)dst + idx * 16);
    }
  };

  auto KSTEP = [&](int kt) {
    const char* Ab_ = (const char*)Ab[kt & 1];
    const char* Bb_ = (const char*)Bb[kt & 1];
#pragma unroll
    for (int ks2 = 0; ks2 < 2; ++ks2) {
      bf16x8 b[4];
#pragma unroll
      for (int j = 0; j < 4; ++j) {
        int col = ncb + j * 16 + llo;
        b[j] = *(const bf16x8*)(Bb_ + col * 128 + ((ks2 * 64 + lhi * 16) ^ ((col & 7) << 4)));
      }
#pragma unroll
      for (int rh = 0; rh < 2; ++rh) {
        bf16x8 a[4];
#pragma unroll
        for (int i = 0; i < 4; ++i) {
          int row = mrb + rh * 64 + i * 16 + llo;
          a[i] = *(const bf16x8*)(Ab_ + row * 128 + ((ks2 * 64 + lhi * 16) ^ ((row & 7) << 4)));
        }
        __builtin_amdgcn_s_setprio(1);
#pragma unroll
        for (int j = 0; j < 4; ++j)
#pragma unroll
          for (int i = 0; i < 4; ++i)
            acc[rh * 4 + i][j] =
                __builtin_amdgcn_mfma_f32_16x16x32_bf16(a[i], b[j], acc[rh * 4 + i][j], 0, 0, 0);
        __builtin_amdgcn_s_setprio(0);
      }
    }
  };

  stageA(0); stageB(0);
  __syncthreads();
  for (int kt = 0; kt < NKT - 1; ++kt) {
    stageA(kt + 1); stageB(kt + 1);
    asm volatile("s_waitcnt vmcnt(8)" ::: "memory");
    __builtin_amdgcn_s_barrier();
    KSTEP(kt);
    asm volatile("s_waitcnt lgkmcnt(0)" ::: "memory");
    __builtin_amdgcn_s_barrier();
  }
  asm volatile("s_waitcnt vmcnt(0)" ::: "memory");
  __builtin_amdgcn_s_barrier();
  KSTEP(NKT - 1);

#pragma unroll
  for (int p = 0; p < 2; ++p) {
    int cw = bc + ncb + p * 32 + llo;
    float bw = b2p[cw];
    float bb = b2p[cw + 16];
    int oc = (bc + ncb + p * 32) / 2 + llo;
#pragma unroll
    for (int fi = 0; fi < 8; ++fi) {
#pragma unroll
      for (int r = 0; r < 4; ++r) {
        int row = mrb + fi * 16 + lhi * 4 + r;
        float wv = acc[fi][2 * p][r] + bw;
        float bv = acc[fi][2 * p + 1][r] + bb;
        out[(bg0 + row) * OC + oc] = inp_lds[row] * wv + bv;
      }
    }
  }
}

extern "C" void kernel_launch(void* const* d_in, const int* in_sizes, int n_in,
                              void* d_out, int out_size, void* d_ws, size_t ws_size,
                              hipStream_t stream) {
  const float* x    = (const float*)d_in[0];
  const float* fc1w = (const float*)d_in[1];
  const float* fc1b = (const float*)d_in[2];
  const float* fc2w = (const float*)d_in[3];
  const float* fc2b = (const float*)d_in[4];
  const float* dil  = (const float*)d_in[5];
  const float* shp  = (const float*)d_in[6];
  float* out = (float*)d_out;

  // ws: fc1wT 512KB | w2pT 4MB | b2p 4KB | ... | hband 64MB at +8MB
  bf16_t* fc1wT = (bf16_t*)d_ws;
  bf16_t* w2pT  = fc1wT + (size_t)HIDD * LATD;
  float*  b2p   = (float*)(w2pT + (size_t)JC * HIDD);
  bf16_t* hband = (bf16_t*)((char*)d_ws + (8u << 20));

  prep_fc1<<<(HIDD * LATD) / 256, 256, 0, stream>>>(fc1w, fc1wT);
  prep_fc2<<<dim3(32, 16), 256, 0, stream>>>(x, fc2w, fc2b, dil, shp, w2pT, b2p);

  for (int band = 0; band < NB / BAND; ++band) {
    h_kernel<<<BAND / 32, 512, 0, stream>>>(x, fc1b, fc1wT, hband, band);
    wag_main<<<(BAND / WBM) * (JC / WBN), 512, 0, stream>>>(
        x, hband, w2pT, b2p, out, band);
  }
}